// Round 1
// baseline (142.437 us; speedup 1.0000x reference)
//
#include <hip/hip_runtime.h>
#include <stdint.h>

// Problem constants (fixed by the reference)
#define BATCH   4096
#define IN_DIM  1024
#define OUT_DIM 1024
// Fused K: 4 control points * 1024, plus 64-column pad carrying alpha/bias
// (x'[m,4096+c]=alpha[m,c], W'[n,4096+c]=bias[c,n], rest zero) so the single
// GEMM computes  out = sum_c alpha*(x.W_c^T) + sum_c alpha*bias  exactly.
#define KDIM    4160

typedef __bf16 bf16x8 __attribute__((ext_vector_type(8)));
typedef float  f32x4  __attribute__((ext_vector_type(4)));

// fp32 -> bf16 bits, round-to-nearest-even
__device__ __forceinline__ uint16_t f2bf(float f) {
    union { float f; uint32_t u; } v; v.f = f;
    uint32_t u = v.u;
    uint32_t r = (u + 0x7FFFu + ((u >> 16) & 1u)) >> 16;
    return (uint16_t)r;
}

// ---------------------------------------------------------------------------
// prep: blocks 0..4095    -> row b of x':  x'[b, c*1024+k] = alpha[b,c]*x[b,k]
//                            pad cols 4096..4159: alpha[b,c] then zeros
//       blocks 4096..5119 -> row n of W':  W'[n, c*1024+k] = W[c,n,k]
//                            pad cols 4096..4159: bias[c,n] then zeros
// ---------------------------------------------------------------------------
__global__ __launch_bounds__(256) void prep(
    const float* __restrict__ x, const float* __restrict__ phase,
    const float* __restrict__ basis, const float* __restrict__ W,
    const float* __restrict__ biases,
    uint16_t* __restrict__ Xp, uint16_t* __restrict__ Wp)
{
    const int bid = blockIdx.x;
    const int tid = threadIdx.x;

    if (bid < BATCH) {
        const int b = bid;
        const float HALF_PI = 1.5707963267948966f;
        float s  = phase[b] / HALF_PI;
        int   q  = (int)floorf(s);
        q = q < 0 ? 0 : (q > 3 ? 3 : q);
        float t  = s - (float)q;
        float t2 = t * t, t3 = t2 * t;

        float coef[4];
#pragma unroll
        for (int j = 0; j < 4; ++j)
            coef[j] = t3 * basis[j] + t2 * basis[4 + j] + t * basis[8 + j] + basis[12 + j];

        // CPI[q][k] = (q+k+3)%4  =>  alpha[c] = coef[(c - q + 1) & 3]
        float alpha[4];
#pragma unroll
        for (int c = 0; c < 4; ++c)
            alpha[c] = coef[(c - q + 1) & 3];

        float4 xv = ((const float4*)(x + (size_t)b * IN_DIM))[tid];
        uint16_t* xrow = Xp + (size_t)b * KDIM;
#pragma unroll
        for (int c = 0; c < 4; ++c) {
            ushort4 o;
            o.x = f2bf(alpha[c] * xv.x);
            o.y = f2bf(alpha[c] * xv.y);
            o.z = f2bf(alpha[c] * xv.z);
            o.w = f2bf(alpha[c] * xv.w);
            ((ushort4*)(xrow + c * IN_DIM))[tid] = o;
        }
        if (tid < 64)
            xrow[4096 + tid] = (tid < 4) ? f2bf(alpha[tid]) : (uint16_t)0;
    } else {
        const int n = bid - BATCH;                 // 0..1023
        uint16_t* wrow = Wp + (size_t)n * KDIM;
#pragma unroll
        for (int c = 0; c < 4; ++c) {
            float4 wv = ((const float4*)(W + ((size_t)c << 20) + (size_t)n * IN_DIM))[tid];
            ushort4 o;
            o.x = f2bf(wv.x); o.y = f2bf(wv.y); o.z = f2bf(wv.z); o.w = f2bf(wv.w);
            ((ushort4*)(wrow + c * IN_DIM))[tid] = o;
        }
        if (tid < 64)
            wrow[4096 + tid] = (tid < 4) ? f2bf(biases[tid * OUT_DIM + n]) : (uint16_t)0;
    }
}

// ---------------------------------------------------------------------------
// gemm_fused: out[m,n] = fp32( sum_ck x'[m,ck] * W'[n,ck] ),  K = 4160
// Tile 128M x 64N, BK=64, 256 threads (2x2 waves, each wave 64x32 via 4x2
// MFMA 16x16x32 fragments). grid = (32 M-tiles, 16 N-tiles) = 512 blocks
// -> 2 blocks/CU (output is only 4Kx1K so this is the occupancy sweet spot
// that keeps a 128-row M tile).
// Staging identical to the verified m97-style path: global_load_lds width 16,
// LDS XOR swizzle applied on the global source address (slice = 8 rows x 64
// cols; lane l -> row l>>3, physical chunk l&7, source chunk (l&7)^(l>>3)).
// Read side: physical chunk = (ks*4 + quad) ^ (lane&7)  [unchanged math].
// Epilogue: plain scalar fp32 stores (16 MB total; prior session measured the
// LDS-repack epilogue as a regression).
// ---------------------------------------------------------------------------
__global__ __launch_bounds__(256, 2) void gemm_fused(
    const uint16_t* __restrict__ Xp, const uint16_t* __restrict__ Wp,
    float* __restrict__ out)
{
    __shared__ uint16_t As[128 * 64];
    __shared__ uint16_t Bs[64 * 64];

    const int tid  = threadIdx.x;
    const int lane = tid & 63;
    const int wid  = tid >> 6;
    const int wm   = wid >> 1;     // 0..1 : which 64-row half of the M tile
    const int wn   = wid & 1;      // 0..1 : which 32-col half of the N tile
    const int tileM = blockIdx.x * 128;
    const int tileN = blockIdx.y * 64;

    f32x4 acc[4][2];
#pragma unroll
    for (int mi = 0; mi < 4; ++mi)
#pragma unroll
        for (int ni = 0; ni < 2; ++ni)
            acc[mi][ni] = (f32x4){0.f, 0.f, 0.f, 0.f};

    const int srow   = lane >> 3;
    const int gchunk = ((lane & 7) ^ srow) * 8;   // element offset of 8-elem chunk

    const uint16_t* Ag = Xp + (size_t)tileM * KDIM;
    const uint16_t* Bg = Wp + (size_t)tileN * KDIM;

    const int quad = lane >> 4;
    const int l7   = lane & 7;

    for (int kt = 0; kt < KDIM / 64; ++kt) {      // 65 K-steps
        const int k0 = kt * 64;
#pragma unroll
        for (int j = 0; j < 4; ++j) {             // A: 16 slices, 4 per wave
            const int s = wid * 4 + j;
            const uint16_t* ga = Ag + (size_t)(s * 8 + srow) * KDIM + k0 + gchunk;
            __builtin_amdgcn_global_load_lds(
                (const __attribute__((address_space(1))) void*)ga,
                (__attribute__((address_space(3))) void*)(As + s * 512), 16, 0, 0);
        }
#pragma unroll
        for (int j = 0; j < 2; ++j) {             // B: 8 slices, 2 per wave
            const int s = wid * 2 + j;
            const uint16_t* gb = Bg + (size_t)(s * 8 + srow) * KDIM + k0 + gchunk;
            __builtin_amdgcn_global_load_lds(
                (const __attribute__((address_space(1))) void*)gb,
                (__attribute__((address_space(3))) void*)(Bs + s * 512), 16, 0, 0);
        }
        __syncthreads();

#pragma unroll
        for (int ks = 0; ks < 2; ++ks) {
            const int ch = (ks * 4 + quad) ^ l7;  // physical chunk
            bf16x8 af[4], bfr[2];
#pragma unroll
            for (int mi = 0; mi < 4; ++mi) {
                const int row = wm * 64 + mi * 16 + (lane & 15);
                af[mi] = *(const bf16x8*)(As + row * 64 + ch * 8);
            }
#pragma unroll
            for (int ni = 0; ni < 2; ++ni) {
                const int row = wn * 32 + ni * 16 + (lane & 15);
                bfr[ni] = *(const bf16x8*)(Bs + row * 64 + ch * 8);
            }
#pragma unroll
            for (int mi = 0; mi < 4; ++mi)
#pragma unroll
                for (int ni = 0; ni < 2; ++ni)
                    acc[mi][ni] = __builtin_amdgcn_mfma_f32_16x16x32_bf16(
                        af[mi], bfr[ni], acc[mi][ni], 0, 0, 0);
        }
        __syncthreads();
    }

    // C/D layout: col = lane&15, row = quad*4 + reg  [m89/m91 verified]
    const int col0 = tileN + wn * 32 + (lane & 15);
#pragma unroll
    for (int mi = 0; mi < 4; ++mi) {
#pragma unroll
        for (int r = 0; r < 4; ++r) {
            const int m = tileM + wm * 64 + mi * 16 + quad * 4 + r;
#pragma unroll
            for (int ni = 0; ni < 2; ++ni)
                out[(size_t)m * OUT_DIM + col0 + ni * 16] = acc[mi][ni][r];
        }
    }
}

extern "C" void kernel_launch(void* const* d_in, const int* in_sizes, int n_in,
                              void* d_out, int out_size, void* d_ws, size_t ws_size,
                              hipStream_t stream)
{
    const float* x       = (const float*)d_in[0];  // (B, IN)
    const float* phase   = (const float*)d_in[1];  // (B,)
    const float* weights = (const float*)d_in[2];  // (4, OUT, IN)
    const float* biases  = (const float*)d_in[3];  // (4, OUT)
    const float* basis   = (const float*)d_in[4];  // (4, 4)
    float* out = (float*)d_out;                    // (B, OUT)

    // Workspace: Xp bf16 (4096 x 4160) = 32.5 MB | Wp bf16 (1024 x 4160) = 8.1 MB
    uint16_t* Xp = (uint16_t*)d_ws;
    uint16_t* Wp = Xp + (size_t)BATCH * KDIM;

    prep<<<BATCH + OUT_DIM, 256, 0, stream>>>(x, phase, basis, weights, biases, Xp, Wp);

    dim3 grid(BATCH / 128, OUT_DIM / 64);          // 512 blocks -> 2/CU
    gemm_fused<<<grid, 256, 0, stream>>>(Xp, Wp, out);
}